// Round 1
// baseline (4196.711 us; speedup 1.0000x reference)
//
#include <hip/hip_runtime.h>

#define NN 30000
#define NE 300000
#define D_IN 256
#define D_H 128
#define D_OUT 64
#define NL 6
#define D_JK (D_H * (NL + 1))   // 896

// ---------------------------------------------------------------------------
// degree count: atomicAdd 1.0f per edge endpoint
// ---------------------------------------------------------------------------
__global__ void degree_kernel(const int* __restrict__ src, const int* __restrict__ dst,
                              float* __restrict__ outdeg, float* __restrict__ indeg) {
    int e = blockIdx.x * blockDim.x + threadIdx.x;
    if (e < NE) {
        atomicAdd(&outdeg[src[e]], 1.0f);
        atomicAdd(&indeg[dst[e]], 1.0f);
    }
}

// v = rsqrt(max(v,1)) in place (covers both deg arrays, contiguous)
__global__ void rsqrt_kernel(float* __restrict__ v, int n) {
    int i = blockIdx.x * blockDim.x + threadIdx.x;
    if (i < n) {
        float d = v[i];
        d = d < 1.0f ? 1.0f : d;
        v[i] = rsqrtf(d);
    }
}

// ---------------------------------------------------------------------------
// fp32 GEMM: Y[n, 0:M] = (X[n, 0:K] @ W[K, M]) * rowscale[n]   (rowscale opt)
// X has row stride ldx. Tiles: 32 rows/block, K chunked by 64.
// LDS ~ 32KB (W chunk, M=128) + 8.7KB (padded X tile) -> 3 blocks/CU.
// ---------------------------------------------------------------------------
template <int M>
__global__ __launch_bounds__(256) void gemm_kernel(
    const float* __restrict__ X, int ldx, int K,
    const float* __restrict__ W,          // [K, M] row-major
    const float* __restrict__ rowscale,   // nullptr => 1.0
    float* __restrict__ Y, int ldy, int nrows)
{
    constexpr int KB = 64;           // K chunk
    constexpr int KBP = KB + 4;      // padded LDS stride (bank-conflict break)
    constexpr int TR = 32;           // rows per block
    constexpr int CG = M / 4;        // col groups (float4)
    constexpr int RG = 256 / CG;     // row groups
    constexpr int RT = TR / RG;      // rows per thread (M=128 -> 4, M=64 -> 2)

    __shared__ float Wl[KB * M];
    __shared__ float Xl[TR * KBP];

    const int tid = threadIdx.x;
    const int cg = tid % CG;
    const int rg = tid / CG;
    const int row0 = blockIdx.x * TR;

    float acc[RT][4];
#pragma unroll
    for (int r = 0; r < RT; r++)
#pragma unroll
        for (int c = 0; c < 4; c++) acc[r][c] = 0.f;

    for (int kb = 0; kb < K; kb += KB) {
        // --- stage W chunk [KB x M] ---
        {
            const float* wsrc = W + (size_t)kb * M;
            constexpr int NV = KB * M / 4 / 256;   // 8 (M=128) / 4 (M=64)
#pragma unroll
            for (int i = 0; i < NV; i++) {
                int idx = (i * 256 + tid) * 4;
                *(float4*)(Wl + idx) = *(const float4*)(wsrc + idx);
            }
        }
        // --- stage X tile [TR x KB] (padded rows) ---
        {
            constexpr int NV = TR * KB / 4 / 256;  // 2
#pragma unroll
            for (int i = 0; i < NV; i++) {
                int flat = i * 256 + tid;
                int r = flat / (KB / 4);
                int c = (flat % (KB / 4)) * 4;
                int grow = row0 + r;
                float4 v = make_float4(0.f, 0.f, 0.f, 0.f);
                if (grow < nrows)
                    v = *(const float4*)(X + (size_t)grow * ldx + kb + c);
                *(float4*)(Xl + r * KBP + c) = v;
            }
        }
        __syncthreads();

#pragma unroll
        for (int k = 0; k < KB; k += 4) {
            float4 w[4];
#pragma unroll
            for (int j = 0; j < 4; j++)
                w[j] = *(const float4*)(Wl + (k + j) * M + cg * 4);
#pragma unroll
            for (int r = 0; r < RT; r++) {
                float4 x = *(const float4*)(Xl + (rg * RT + r) * KBP + k);
                acc[r][0] += x.x * w[0].x + x.y * w[1].x + x.z * w[2].x + x.w * w[3].x;
                acc[r][1] += x.x * w[0].y + x.y * w[1].y + x.z * w[2].y + x.w * w[3].y;
                acc[r][2] += x.x * w[0].z + x.y * w[1].z + x.z * w[2].z + x.w * w[3].z;
                acc[r][3] += x.x * w[0].w + x.y * w[1].w + x.z * w[2].w + x.w * w[3].w;
            }
        }
        __syncthreads();
    }

#pragma unroll
    for (int r = 0; r < RT; r++) {
        int grow = row0 + rg * RT + r;
        if (grow < nrows) {
            float s = rowscale ? rowscale[grow] : 1.0f;
            float4 v = make_float4(acc[r][0] * s, acc[r][1] * s, acc[r][2] * s, acc[r][3] * s);
            *(float4*)(Y + (size_t)grow * ldy + cg * 4) = v;
        }
    }
}

// ---------------------------------------------------------------------------
// edge scatter: agg[dst[e], :] += T[src[e], :]   (D = 128 or 64)
// one thread per (edge, 4 dims): float4 gather + 4 atomicAdds
// ---------------------------------------------------------------------------
template <int D>
__global__ void scatter_add_kernel(const float* __restrict__ T,
                                   const int* __restrict__ src,
                                   const int* __restrict__ dst,
                                   float* __restrict__ agg) {
    constexpr int Q = D / 4;
    int idx = blockIdx.x * blockDim.x + threadIdx.x;
    int e = idx / Q;
    int q = idx % Q;
    if (e < NE) {
        int s = src[e], d = dst[e];
        float4 v = *(const float4*)(T + (size_t)s * D + q * 4);
        float* p = agg + (size_t)d * D + q * 4;
        atomicAdd(p + 0, v.x);
        atomicAdd(p + 1, v.y);
        atomicAdd(p + 2, v.z);
        atomicAdd(p + 3, v.w);
    }
}

// ---------------------------------------------------------------------------
// h = relu(agg * inv_in + bias) written into jk block (row stride 896)
// ---------------------------------------------------------------------------
__global__ void finalize_kernel(const float* __restrict__ agg,
                                const float* __restrict__ inv_in,
                                const float* __restrict__ bias,   // [128]
                                float* __restrict__ jk_out) {      // jk + l*128
    int idx = blockIdx.x * blockDim.x + threadIdx.x;   // over NN*32
    int node = idx / 32;
    int q = idx % 32;
    if (node < NN) {
        float s = inv_in[node];
        float4 a = *(const float4*)(agg + (size_t)node * D_H + q * 4);
        float4 b = *(const float4*)(bias + q * 4);
        float4 h;
        h.x = fmaxf(fmaf(a.x, s, b.x), 0.f);
        h.y = fmaxf(fmaf(a.y, s, b.y), 0.f);
        h.z = fmaxf(fmaf(a.z, s, b.z), 0.f);
        h.w = fmaxf(fmaf(a.w, s, b.w), 0.f);
        *(float4*)(jk_out + (size_t)node * D_JK + q * 4) = h;
    }
}

// out[n, :] += bout  (in place, after scatter into d_out)
__global__ void bias_add_kernel(float* __restrict__ out, const float* __restrict__ bout) {
    int idx = blockIdx.x * blockDim.x + threadIdx.x;   // over NN*16
    int node = idx / 16;
    int q = idx % 16;
    if (node < NN) {
        float4 v = *(float4*)(out + (size_t)node * D_OUT + q * 4);
        float4 b = *(const float4*)(bout + q * 4);
        v.x += b.x; v.y += b.y; v.z += b.z; v.w += b.w;
        *(float4*)(out + (size_t)node * D_OUT + q * 4) = v;
    }
}

// ---------------------------------------------------------------------------
extern "C" void kernel_launch(void* const* d_in, const int* in_sizes, int n_in,
                              void* d_out, int out_size, void* d_ws, size_t ws_size,
                              hipStream_t stream) {
    const float* feats = (const float*)d_in[0];
    const int*   src   = (const int*)d_in[1];
    const int*   dst   = (const int*)d_in[2];
    const float* W0    = (const float*)d_in[3];
    const float* b0    = (const float*)d_in[4];
    const float* Wh    = (const float*)d_in[5];   // [6,128,128]
    const float* bh    = (const float*)d_in[6];   // [6,128]
    const float* Wout  = (const float*)d_in[7];   // [896,64]
    const float* bout  = (const float*)d_in[8];
    float* out = (float*)d_out;

    float* ws      = (float*)d_ws;
    float* inv_out = ws;                        // NN
    float* inv_in  = ws + NN;                   // NN
    float* t       = ws + 2 * NN;               // NN*128  (also reused for p [NN*64])
    float* agg     = t + (size_t)NN * D_H;      // NN*128
    float* jk      = agg + (size_t)NN * D_H;    // NN*896

    const int B = 256;
    const int gemm_blocks = (NN + 31) / 32;     // 938

    // degrees -> inv sqrt
    hipMemsetAsync(inv_out, 0, 2 * NN * sizeof(float), stream);
    degree_kernel<<<(NE + B - 1) / B, B, 0, stream>>>(src, dst, inv_out, inv_in);
    rsqrt_kernel<<<(2 * NN + B - 1) / B, B, 0, stream>>>(inv_out, 2 * NN);

    // layer 0: feats [N,256] @ W0 [256,128]
    gemm_kernel<128><<<gemm_blocks, B, 0, stream>>>(feats, D_IN, D_IN, W0, inv_out, t, D_H, NN);
    hipMemsetAsync(agg, 0, (size_t)NN * D_H * sizeof(float), stream);
    scatter_add_kernel<128><<<(NE * 32 + B - 1) / B, B, 0, stream>>>(t, src, dst, agg);
    finalize_kernel<<<(NN * 32 + B - 1) / B, B, 0, stream>>>(agg, inv_in, b0, jk);

    // layers 1..6: h_l [N,128] @ Wh[l] [128,128]
    for (int l = 0; l < NL; l++) {
        gemm_kernel<128><<<gemm_blocks, B, 0, stream>>>(
            jk + (size_t)l * D_H, D_JK, D_H, Wh + (size_t)l * D_H * D_H, inv_out, t, D_H, NN);
        hipMemsetAsync(agg, 0, (size_t)NN * D_H * sizeof(float), stream);
        scatter_add_kernel<128><<<(NE * 32 + B - 1) / B, B, 0, stream>>>(t, src, dst, agg);
        finalize_kernel<<<(NN * 32 + B - 1) / B, B, 0, stream>>>(
            agg, inv_in, bh + (size_t)l * D_H, jk + (size_t)(l + 1) * D_H);
    }

    // final: p = jk [N,896] @ Wout [896,64]; out = segsum(p[src]) + bout
    gemm_kernel<64><<<gemm_blocks, B, 0, stream>>>(jk, D_JK, D_JK, Wout, nullptr, t, D_OUT, NN);
    hipMemsetAsync(out, 0, (size_t)NN * D_OUT * sizeof(float), stream);
    scatter_add_kernel<64><<<(NE * 16 + B - 1) / B, B, 0, stream>>>(t, src, dst, out);
    bias_add_kernel<<<(NN * 16 + B - 1) / B, B, 0, stream>>>(out, bout);
}

// Round 2
// 636.536 us; speedup vs baseline: 6.5930x; 6.5930x over previous
//
#include <hip/hip_runtime.h>

#define NN 30000
#define NE 300000
#define D_IN 256
#define D_H 128
#define D_OUT 64
#define NL 6
#define D_JK (D_H * (NL + 1))   // 896

// ---------------------------------------------------------------------------
// int degree count per endpoint
// ---------------------------------------------------------------------------
__global__ void degree_kernel(const int* __restrict__ src, const int* __restrict__ dst,
                              int* __restrict__ outdeg, int* __restrict__ indeg) {
    int e = blockIdx.x * blockDim.x + threadIdx.x;
    if (e < NE) {
        atomicAdd(&outdeg[src[e]], 1);
        atomicAdd(&indeg[dst[e]], 1);
    }
}

// inv[i] = rsqrt(max(deg,1)) for both arrays (contiguous int -> float)
__global__ void rsqrt_kernel(const int* __restrict__ deg, float* __restrict__ inv, int n) {
    int i = blockIdx.x * blockDim.x + threadIdx.x;
    if (i < n) {
        float d = (float)deg[i];
        inv[i] = rsqrtf(d < 1.0f ? 1.0f : d);
    }
}

// ---------------------------------------------------------------------------
// exclusive prefix scan of indeg[NN] -> row_ptr[NN+1], single block 1024 thr
// ---------------------------------------------------------------------------
__global__ __launch_bounds__(1024) void scan_kernel(const int* __restrict__ deg,
                                                    int* __restrict__ row_ptr) {
    __shared__ int sm[1024];
    __shared__ int running;
    if (threadIdx.x == 0) running = 0;
    __syncthreads();
    for (int base = 0; base < NN; base += 1024) {
        int i = base + threadIdx.x;
        int v = (i < NN) ? deg[i] : 0;
        sm[threadIdx.x] = v;
        __syncthreads();
        for (int off = 1; off < 1024; off <<= 1) {
            int t = (threadIdx.x >= off) ? sm[threadIdx.x - off] : 0;
            __syncthreads();
            sm[threadIdx.x] += t;
            __syncthreads();
        }
        int incl = sm[threadIdx.x];
        if (i < NN) row_ptr[i] = running + incl - v;
        int total = sm[1023];
        __syncthreads();
        if (threadIdx.x == 0) running += total;
        __syncthreads();
    }
    if (threadIdx.x == 0) row_ptr[NN] = running;
}

// scatter edge sources into CSR col array (grouped by dst)
__global__ void fill_kernel(const int* __restrict__ src, const int* __restrict__ dst,
                            const int* __restrict__ row_ptr, int* __restrict__ cursor,
                            int* __restrict__ col) {
    int e = blockIdx.x * blockDim.x + threadIdx.x;
    if (e < NE) {
        int d = dst[e];
        int pos = atomicAdd(&cursor[d], 1);
        col[row_ptr[d] + pos] = src[e];
    }
}

// ---------------------------------------------------------------------------
// fp32 GEMM: Y[n, 0:M] = (X[n, 0:K] @ W[K, M]) * rowscale[n]   (rowscale opt)
// ---------------------------------------------------------------------------
template <int M>
__global__ __launch_bounds__(256) void gemm_kernel(
    const float* __restrict__ X, int ldx, int K,
    const float* __restrict__ W,          // [K, M] row-major
    const float* __restrict__ rowscale,   // nullptr => 1.0
    float* __restrict__ Y, int ldy, int nrows)
{
    constexpr int KB = 64;
    constexpr int KBP = KB + 4;
    constexpr int TR = 32;
    constexpr int CG = M / 4;
    constexpr int RG = 256 / CG;
    constexpr int RT = TR / RG;

    __shared__ float Wl[KB * M];
    __shared__ float Xl[TR * KBP];

    const int tid = threadIdx.x;
    const int cg = tid % CG;
    const int rg = tid / CG;
    const int row0 = blockIdx.x * TR;

    float acc[RT][4];
#pragma unroll
    for (int r = 0; r < RT; r++)
#pragma unroll
        for (int c = 0; c < 4; c++) acc[r][c] = 0.f;

    for (int kb = 0; kb < K; kb += KB) {
        {
            const float* wsrc = W + (size_t)kb * M;
            constexpr int NV = KB * M / 4 / 256;
#pragma unroll
            for (int i = 0; i < NV; i++) {
                int idx = (i * 256 + tid) * 4;
                *(float4*)(Wl + idx) = *(const float4*)(wsrc + idx);
            }
        }
        {
            constexpr int NV = TR * KB / 4 / 256;
#pragma unroll
            for (int i = 0; i < NV; i++) {
                int flat = i * 256 + tid;
                int r = flat / (KB / 4);
                int c = (flat % (KB / 4)) * 4;
                int grow = row0 + r;
                float4 v = make_float4(0.f, 0.f, 0.f, 0.f);
                if (grow < nrows)
                    v = *(const float4*)(X + (size_t)grow * ldx + kb + c);
                *(float4*)(Xl + r * KBP + c) = v;
            }
        }
        __syncthreads();

#pragma unroll
        for (int k = 0; k < KB; k += 4) {
            float4 w[4];
#pragma unroll
            for (int j = 0; j < 4; j++)
                w[j] = *(const float4*)(Wl + (k + j) * M + cg * 4);
#pragma unroll
            for (int r = 0; r < RT; r++) {
                float4 x = *(const float4*)(Xl + (rg * RT + r) * KBP + k);
                acc[r][0] += x.x * w[0].x + x.y * w[1].x + x.z * w[2].x + x.w * w[3].x;
                acc[r][1] += x.x * w[0].y + x.y * w[1].y + x.z * w[2].y + x.w * w[3].y;
                acc[r][2] += x.x * w[0].z + x.y * w[1].z + x.z * w[2].z + x.w * w[3].z;
                acc[r][3] += x.x * w[0].w + x.y * w[1].w + x.z * w[2].w + x.w * w[3].w;
            }
        }
        __syncthreads();
    }

#pragma unroll
    for (int r = 0; r < RT; r++) {
        int grow = row0 + rg * RT + r;
        if (grow < nrows) {
            float s = rowscale ? rowscale[grow] : 1.0f;
            float4 v = make_float4(acc[r][0] * s, acc[r][1] * s, acc[r][2] * s, acc[r][3] * s);
            *(float4*)(Y + (size_t)grow * ldy + cg * 4) = v;
        }
    }
}

// ---------------------------------------------------------------------------
// CSR gather-reduce + epilogue:
//   Y[node, 0:D] = act( (sum_{j in in(node)} T[col[j], :]) * scale[node] + bias )
// thread = (node, 4-dim group). No atomics.
// ---------------------------------------------------------------------------
template <int D, bool RELU>
__global__ void gather_kernel(const float* __restrict__ T,
                              const int* __restrict__ row_ptr,
                              const int* __restrict__ col,
                              const float* __restrict__ scale,  // nullptr => 1
                              const float* __restrict__ bias,   // [D]
                              float* __restrict__ Y, int ldy) {
    constexpr int Q = D / 4;
    int idx = blockIdx.x * blockDim.x + threadIdx.x;
    int node = idx / Q;
    int q = idx % Q;
    if (node >= NN) return;
    int beg = row_ptr[node];
    int end = row_ptr[node + 1];
    float4 acc = make_float4(0.f, 0.f, 0.f, 0.f);
    int j = beg;
    // 2x unrolled for ILP
    for (; j + 1 < end; j += 2) {
        int c0 = col[j], c1 = col[j + 1];
        float4 v0 = *(const float4*)(T + (size_t)c0 * D + q * 4);
        float4 v1 = *(const float4*)(T + (size_t)c1 * D + q * 4);
        acc.x += v0.x + v1.x;
        acc.y += v0.y + v1.y;
        acc.z += v0.z + v1.z;
        acc.w += v0.w + v1.w;
    }
    if (j < end) {
        int c0 = col[j];
        float4 v0 = *(const float4*)(T + (size_t)c0 * D + q * 4);
        acc.x += v0.x; acc.y += v0.y; acc.z += v0.z; acc.w += v0.w;
    }
    float s = scale ? scale[node] : 1.0f;
    float4 b = *(const float4*)(bias + q * 4);
    float4 h;
    h.x = fmaf(acc.x, s, b.x);
    h.y = fmaf(acc.y, s, b.y);
    h.z = fmaf(acc.z, s, b.z);
    h.w = fmaf(acc.w, s, b.w);
    if (RELU) {
        h.x = fmaxf(h.x, 0.f); h.y = fmaxf(h.y, 0.f);
        h.z = fmaxf(h.z, 0.f); h.w = fmaxf(h.w, 0.f);
    }
    *(float4*)(Y + (size_t)node * ldy + q * 4) = h;
}

// ---------------------------------------------------------------------------
extern "C" void kernel_launch(void* const* d_in, const int* in_sizes, int n_in,
                              void* d_out, int out_size, void* d_ws, size_t ws_size,
                              hipStream_t stream) {
    const float* feats = (const float*)d_in[0];
    const int*   src   = (const int*)d_in[1];
    const int*   dst   = (const int*)d_in[2];
    const float* W0    = (const float*)d_in[3];
    const float* b0    = (const float*)d_in[4];
    const float* Wh    = (const float*)d_in[5];   // [6,128,128]
    const float* bh    = (const float*)d_in[6];   // [6,128]
    const float* Wout  = (const float*)d_in[7];   // [896,64]
    const float* bout  = (const float*)d_in[8];
    float* out = (float*)d_out;

    // workspace layout (floats/ints)
    float* ws      = (float*)d_ws;
    float* inv_out = ws;                          // NN
    float* inv_in  = ws + NN;                     // NN
    float* t       = ws + 2 * NN;                 // NN*128
    float* jk      = t + (size_t)NN * D_H;        // NN*896
    int* ibase     = (int*)(jk + (size_t)NN * D_JK);
    int* outdeg_i  = ibase;                       // NN
    int* indeg_i   = ibase + NN;                  // NN
    int* row_ptr   = ibase + 2 * NN;              // NN+1
    int* cursor    = ibase + 3 * NN + 1;          // NN
    int* col       = ibase + 4 * NN + 1;          // NE

    const int B = 256;
    const int gemm_blocks = (NN + 31) / 32;

    // ---- CSR build + norms ----
    hipMemsetAsync(outdeg_i, 0, 2 * NN * sizeof(int), stream);       // outdeg+indeg
    hipMemsetAsync(cursor, 0, NN * sizeof(int), stream);
    degree_kernel<<<(NE + B - 1) / B, B, 0, stream>>>(src, dst, outdeg_i, indeg_i);
    rsqrt_kernel<<<(2 * NN + B - 1) / B, B, 0, stream>>>(outdeg_i, inv_out, 2 * NN);
    scan_kernel<<<1, 1024, 0, stream>>>(indeg_i, row_ptr);
    fill_kernel<<<(NE + B - 1) / B, B, 0, stream>>>(src, dst, row_ptr, cursor, col);

    // ---- layer 0: t = (feats @ W0)*inv_out ; jk[:,0:128] = relu(gather*inv_in + b0)
    gemm_kernel<128><<<gemm_blocks, B, 0, stream>>>(feats, D_IN, D_IN, W0, inv_out, t, D_H, NN);
    gather_kernel<128, true><<<(NN * 32 + B - 1) / B, B, 0, stream>>>(
        t, row_ptr, col, inv_in, b0, jk, D_JK);

    // ---- layers 1..6
    for (int l = 0; l < NL; l++) {
        gemm_kernel<128><<<gemm_blocks, B, 0, stream>>>(
            jk + (size_t)l * D_H, D_JK, D_H, Wh + (size_t)l * D_H * D_H, inv_out, t, D_H, NN);
        gather_kernel<128, true><<<(NN * 32 + B - 1) / B, B, 0, stream>>>(
            t, row_ptr, col, inv_in, bh + (size_t)l * D_H, jk + (size_t)(l + 1) * D_H, D_JK);
    }

    // ---- final: p = jk @ Wout ; out = gather(p) + bout (no norm, no relu)
    gemm_kernel<64><<<gemm_blocks, B, 0, stream>>>(jk, D_JK, D_JK, Wout, nullptr, t, D_OUT, NN);
    gather_kernel<64, false><<<(NN * 16 + B - 1) / B, B, 0, stream>>>(
        t, row_ptr, col, nullptr, bout, out, D_OUT);
}